// Round 4
// 581.178 us; speedup vs baseline: 1.0127x; 1.0127x over previous
//
#include <hip/hip_runtime.h>
#include <stdint.h>

typedef unsigned short u16;
typedef __bf16 bf16x8 __attribute__((ext_vector_type(8)));
typedef float floatx4 __attribute__((ext_vector_type(4)));

// ---------------- fused global amax (x and W in one launch) ----------------
__global__ void amax_both_k(const float4* __restrict__ x, long nx4,
                            const float4* __restrict__ w, long nw4,
                            unsigned* slots, int gx) {
    const float4* src; long n4; int bid, nb; unsigned* slot;
    if ((int)blockIdx.x < gx) { src = x; n4 = nx4; bid = blockIdx.x; nb = gx; slot = slots; }
    else { src = w; n4 = nw4; bid = blockIdx.x - gx; nb = gridDim.x - gx; slot = slots + 1; }
    float m = 0.0f;
    long stride = (long)nb * blockDim.x;
    for (long i = (long)bid * blockDim.x + threadIdx.x; i < n4; i += stride) {
        float4 v = src[i];
        m = fmaxf(m, fmaxf(fmaxf(fabsf(v.x), fabsf(v.y)), fmaxf(fabsf(v.z), fabsf(v.w))));
    }
    #pragma unroll
    for (int off = 32; off > 0; off >>= 1)
        m = fmaxf(m, __shfl_down(m, off, 64));
    __shared__ float sm[4];
    int lane = threadIdx.x & 63, wv = threadIdx.x >> 6;
    if (lane == 0) sm[wv] = m;
    __syncthreads();
    if (threadIdx.x == 0) {
        m = fmaxf(fmaxf(sm[0], sm[1]), fmaxf(sm[2], sm[3]));
        atomicMax(slot, __float_as_uint(m));   // nonneg fp32: uint order == float order
    }
}

// ---------------- quantization helpers ----------------
// RNE float -> e4m3fn for v in [0, 448]
__device__ __forceinline__ float e4m3_rne(float v) {
    unsigned u = __float_as_uint(v);
    u += 0x7FFFFu + ((u >> 20) & 1u);            // RNE keep 3 mantissa bits
    float hi = __uint_as_float(u & 0xFFF00000u);
    float lo = rintf(v * 512.0f) * 0.001953125f; // subnormal, step 2^-9
    return (v < 0.015625f) ? lo : hi;
}

// RNE to fp4 e2m1 {0,±0.5,1,1.5,2,3,4,6}
__device__ __forceinline__ float fp4_rne(float x) {
    float a = fminf(fabsf(x), 6.0f);
    unsigned u = __float_as_uint(a);
    u += 0x1FFFFFu + ((u >> 22) & 1u);           // RNE keep 1 mantissa bit (a >= 1)
    float hi = __uint_as_float(u & 0xFFC00000u);
    float lo = rintf(a + a) * 0.5f;              // a < 1: fixed step 0.5
    float q = (a < 1.0f) ? lo : hi;
    return copysignf(q, x);
}

// pack two fp32 (exactly representable in bf16) into 2 bf16 bit patterns
__device__ __forceinline__ unsigned pack2(float d0, float d1) {
    return (__float_as_uint(d0) >> 16) | (__float_as_uint(d1) & 0xFFFF0000u);
}

// One thread per 16-elem nvfp4 block; handles both tensors in one launch.
__global__ void quant_both_k(const float* __restrict__ x, const float* __restrict__ W,
                             u16* __restrict__ Aq, u16* __restrict__ Bq,
                             const unsigned* __restrict__ slots, long nbx, long nbtot) {
    long b = (long)blockIdx.x * blockDim.x + threadIdx.x;
    if (b >= nbtot) return;
    const float* src; u16* dst; float ag;
    if (b < nbx) { src = x + b * 16; dst = Aq + b * 16; ag = __uint_as_float(slots[0]); }
    else { long c = b - nbx; src = W + c * 16; dst = Bq + c * 16; ag = __uint_as_float(slots[1]); }
    float gs = 2688.0f / ag;       // same fp32 ops as reference
    float t  = gs / 6.0f;          // reference computes gs/F4_MAX first
    const float4* p = (const float4*)src;
    float4 v0 = p[0], v1 = p[1], v2 = p[2], v3 = p[3];
    float am = 0.0f;
    am = fmaxf(am, fmaxf(fmaxf(fabsf(v0.x), fabsf(v0.y)), fmaxf(fabsf(v0.z), fabsf(v0.w))));
    am = fmaxf(am, fmaxf(fmaxf(fabsf(v1.x), fabsf(v1.y)), fmaxf(fabsf(v1.z), fabsf(v1.w))));
    am = fmaxf(am, fmaxf(fmaxf(fabsf(v2.x), fabsf(v2.y)), fmaxf(fabsf(v2.z), fabsf(v2.w))));
    am = fmaxf(am, fmaxf(fmaxf(fabsf(v3.x), fabsf(v3.y)), fmaxf(fabsf(v3.z), fabsf(v3.w))));
    float sf = e4m3_rne(am * t);
    float r = gs / (sf > 0.0f ? sf : 1.0f);      // reference: gs/safe, then v*r
    uint4 o0, o1;
    o0.x = pack2(fp4_rne(v0.x * r) * sf, fp4_rne(v0.y * r) * sf);
    o0.y = pack2(fp4_rne(v0.z * r) * sf, fp4_rne(v0.w * r) * sf);
    o0.z = pack2(fp4_rne(v1.x * r) * sf, fp4_rne(v1.y * r) * sf);
    o0.w = pack2(fp4_rne(v1.z * r) * sf, fp4_rne(v1.w * r) * sf);
    o1.x = pack2(fp4_rne(v2.x * r) * sf, fp4_rne(v2.y * r) * sf);
    o1.y = pack2(fp4_rne(v2.z * r) * sf, fp4_rne(v2.w * r) * sf);
    o1.z = pack2(fp4_rne(v3.x * r) * sf, fp4_rne(v3.y * r) * sf);
    o1.w = pack2(fp4_rne(v3.z * r) * sf, fp4_rne(v3.w * r) * sf);
    uint4* q = (uint4*)dst;
    q[0] = o0; q[1] = o1;
}

// ---------------- GEMM: 256x256 tile, BK=64, 8-phase counted-vmcnt schedule ----------------
// 8 waves (2M x 4N), per-wave 128x64 output, 16x16x32 bf16 MFMA (8x4 frags).
// LDS: A,B each 2 x 256x64 bf16 (64 KB each, 128 KB total) = K-tile double buffer.
// XOR-(row&7) 16B-chunk swizzle on staging source + ds_read (T2); 16x16 frags -> 2-way max (free).
// Stage schedule per tile s (1 half-tile = 128 rows x 64 cols per phase):
//   ph1: A(s+1)h0 -> bufA[s^1]   (A(s-1) retired at s-1:ph3 barrier)
//   ph2: A(s+1)h1
//   ph3: B(s+2)h0 -> bufB[s&1]   (B(s) retired at s:ph2 barrier)
//   ph4: B(s+2)h1, then s_waitcnt vmcnt(4) + barrier  (leaves exactly B(s+2) in flight)
// => at each tile boundary, tile s+1's A (issued >=2 slots back) and B (issued last tile) are resident.
// End tiles issue clamped dummy stages into dead buffers to keep vmcnt counts uniform.
#define KTILE 64

#define SFENCE() __builtin_amdgcn_sched_barrier(0)
#define BAR() do { asm volatile("" ::: "memory"); SFENCE(); \
    __builtin_amdgcn_s_barrier(); SFENCE(); asm volatile("" ::: "memory"); } while (0)

#define STAGE_SLOT(GS, LS) do { \
    __builtin_amdgcn_global_load_lds((const __attribute__((address_space(1))) void*)(GS), \
        (__attribute__((address_space(3))) void*)(LS), 16, 0, 0); \
    __builtin_amdgcn_global_load_lds((const __attribute__((address_space(1))) void*)((GS) + row64K), \
        (__attribute__((address_space(3))) void*)((LS) + 4096), 16, 0, 0); \
} while (0)

#define LDA(CUR, MH) do { \
    _Pragma("unroll") for (int mf = 0; mf < 4; ++mf) { \
        const u16* p_ = aB + (CUR) * 16384 + ((MH) * 64 + mf * 16) * 64; \
        af[mf][0] = *(const bf16x8*)(p_ + ca0 * 8); \
        af[mf][1] = *(const bf16x8*)(p_ + ca1 * 8); \
    } } while (0)

#define LDB(CUR, NH) do { \
    _Pragma("unroll") for (int nf = 0; nf < 2; ++nf) { \
        const u16* p_ = bB + (CUR) * 16384 + ((NH) * 32 + nf * 16) * 64; \
        bf[(NH)*2+nf][0] = *(const bf16x8*)(p_ + ca0 * 8); \
        bf[(NH)*2+nf][1] = *(const bf16x8*)(p_ + ca1 * 8); \
    } } while (0)

#define QUAD(MH, NH) do { \
    _Pragma("unroll") for (int ks = 0; ks < 2; ++ks) \
    _Pragma("unroll") for (int mf = 0; mf < 4; ++mf) \
    _Pragma("unroll") for (int nf = 0; nf < 2; ++nf) \
        acc[(MH)*4+mf][(NH)*2+nf] = __builtin_amdgcn_mfma_f32_16x16x32_bf16( \
            af[mf][ks], bf[(NH)*2+nf][ks], acc[(MH)*4+mf][(NH)*2+nf], 0, 0, 0); \
} while (0)

#define TILE(CUR, S) do { \
    const u16* gA1 = Ag + (size_t)(((S)+1 < NT) ? (S)+1 : NT-1) * KTILE; \
    const u16* gB2 = Bg + (size_t)(((S)+2 < NT) ? (S)+2 : NT-1) * KTILE; \
    u16* lA1 = Al + ((CUR)^1) * 16384; \
    u16* lB2 = Bl + (CUR) * 16384; \
    /* phase 1: quadrant (0,0) */ \
    LDA(CUR, 0); LDB(CUR, 0); \
    STAGE_SLOT(gA1, lA1); \
    BAR(); \
    __builtin_amdgcn_s_setprio(1); QUAD(0, 0); __builtin_amdgcn_s_setprio(0); \
    BAR(); \
    /* phase 2: quadrant (0,1) */ \
    LDB(CUR, 1); \
    STAGE_SLOT(gA1 + halfGA, lA1 + 8192); \
    BAR(); \
    __builtin_amdgcn_s_setprio(1); QUAD(0, 1); __builtin_amdgcn_s_setprio(0); \
    BAR(); \
    /* phase 3: quadrant (1,0) */ \
    LDA(CUR, 1); \
    STAGE_SLOT(gB2, lB2); \
    BAR(); \
    __builtin_amdgcn_s_setprio(1); QUAD(1, 0); __builtin_amdgcn_s_setprio(0); \
    BAR(); \
    /* phase 4: quadrant (1,1) + per-tile counted-vmcnt checkpoint */ \
    STAGE_SLOT(gB2 + halfGA, lB2 + 8192); \
    BAR(); \
    __builtin_amdgcn_s_setprio(1); QUAD(1, 1); __builtin_amdgcn_s_setprio(0); \
    SFENCE(); \
    asm volatile("s_waitcnt vmcnt(4)" ::: "memory"); \
    BAR(); \
} while (0)

__global__ __launch_bounds__(512, 2) void gemm_k(
    const u16* __restrict__ A, const u16* __restrict__ B,
    const float* __restrict__ bias, const unsigned* __restrict__ scal,
    float* __restrict__ out, int M, int N, int K)
{
    __shared__ u16 As[2 * 256 * 64];   // 64 KB
    __shared__ u16 Bs[2 * 256 * 64];   // 64 KB

    const int tid = threadIdx.x;       // 0..511
    const int l   = tid & 63;
    const int wv  = tid >> 6;          // 0..7
    const int wm  = wv >> 2;           // 0..1  (M half)
    const int wn  = wv & 3;            // 0..3  (N quarter)

    // XCD-aware bijective block swizzle (m204)
    const int nTM = M / 256, nTN = N / 256;
    const int nwg = nTM * nTN;
    const int orig = blockIdx.x;
    const int xcd = orig & 7, lid = orig >> 3;
    const int q8 = nwg >> 3, r8 = nwg & 7;
    const int swz = (xcd < r8 ? xcd * (q8 + 1) : r8 * (q8 + 1) + (xcd - r8) * q8) + lid;
    const long tileM = (long)(swz % nTM) * 256;
    const long tileN = (long)(swz / nTM) * 256;

    // ---- staging addresses (per-lane global src, wave-uniform LDS dst) ----
    const int srow  = tid >> 3;              // 0..63 within half
    const int sslot = tid & 7;               // 16B chunk slot
    const int schunk = sslot ^ (srow & 7);   // inverse-swizzled source chunk
    const size_t row64K = (size_t)64 * K;
    const size_t halfGA = (size_t)128 * K;
    const u16* Ag = A + (size_t)(tileM + srow) * K + schunk * 8;
    const u16* Bg = B + (size_t)(tileN + srow) * K + schunk * 8;
    u16* Al = As + wv * 512;                 // wave-linear dest (base + lane*16B)
    u16* Bl = Bs + wv * 512;

    // ---- ds_read addresses (16x16x32 frag: row = l&15, kchunk = l>>4) ----
    const int lr = l & 15;
    const int hi = l >> 4;
    const int ca0 = hi ^ (lr & 7);           // swizzled chunk, ks=0
    const int ca1 = ca0 ^ 4;                 // ks=1 toggles chunk bit2
    const u16* aB = As + (wm * 128 + lr) * 64;
    const u16* bB = Bs + (wn * 64 + lr) * 64;

    floatx4 acc[8][4] = {};
    bf16x8 af[4][2], bf[4][2];

    const int NT = K / KTILE;                // must be even (K % 128 == 0)

    // ---- prologue: B(0), A(0), B(1); leave B(1) (last 2 slots) in flight ----
    STAGE_SLOT(Bg, Bl);
    STAGE_SLOT(Bg + halfGA, Bl + 8192);
    STAGE_SLOT(Ag, Al);
    STAGE_SLOT(Ag + halfGA, Al + 8192);
    {
        const u16* gB1 = Bg + ((1 < NT) ? KTILE : 0);
        STAGE_SLOT(gB1, Bl + 16384);
        STAGE_SLOT(gB1 + halfGA, Bl + 16384 + 8192);
    }
    SFENCE();
    asm volatile("s_waitcnt vmcnt(4)" ::: "memory");
    BAR();

    for (int s = 0; s < NT; s += 2) {
        TILE(0, s);
        TILE(1, s + 1);
    }

    // ---- epilogue ----
    float ax = __uint_as_float(scal[0]);
    float aw = __uint_as_float(scal[1]);
    float gsx = 2688.0f / ax, gsw = 2688.0f / aw;
    float alpha = 1.0f / (gsx * gsw);

    // C/D (m89): col = lane&15, row = (lane>>4)*4 + reg
    #pragma unroll
    for (int nq = 0; nq < 4; ++nq) {
        const long col = tileN + wn * 64 + nq * 16 + lr;
        const float bv = bias[col];
        #pragma unroll
        for (int mq = 0; mq < 8; ++mq) {
            const long r0 = tileM + wm * 128 + mq * 16 + hi * 4;
            #pragma unroll
            for (int reg = 0; reg < 4; ++reg)
                out[(size_t)(r0 + reg) * N + col] = acc[mq][nq][reg] * alpha + bv;
        }
    }
}

// ---------------- launch ----------------
extern "C" void kernel_launch(void* const* d_in, const int* in_sizes, int n_in,
                              void* d_out, int out_size, void* d_ws, size_t ws_size,
                              hipStream_t stream) {
    const float* x    = (const float*)d_in[0];
    const float* W    = (const float*)d_in[1];
    const float* bias = (const float*)d_in[2];
    float* out = (float*)d_out;

    const int N = in_sizes[2];
    const int K = in_sizes[1] / N;
    const int M = in_sizes[0] / K;

    unsigned* scal = (unsigned*)d_ws;
    u16* Aq = (u16*)((char*)d_ws + 256);
    u16* Bq = Aq + (size_t)M * K;

    hipMemsetAsync(scal, 0, 8, stream);

    const int GX = 2048, GW = 1024;
    hipLaunchKernelGGL(amax_both_k, dim3(GX + GW), dim3(256), 0, stream,
                       (const float4*)x, (long)M * K / 4,
                       (const float4*)W, (long)N * K / 4, scal, GX);

    long nbx = (long)M * K / 16;
    long nbw = (long)N * K / 16;
    hipLaunchKernelGGL(quant_both_k, dim3((unsigned)((nbx + nbw + 255) / 256)), dim3(256), 0, stream,
                       x, W, Aq, Bq, scal, nbx, nbx + nbw);

    hipLaunchKernelGGL(gemm_k, dim3((M / 256) * (N / 256)), dim3(512), 0, stream,
                       Aq, Bq, bias, scal, out, M, N, K);
}

// Round 5
// 524.411 us; speedup vs baseline: 1.1223x; 1.1083x over previous
//
#include <hip/hip_runtime.h>
#include <stdint.h>

typedef unsigned short u16;
typedef __bf16 bf16x8 __attribute__((ext_vector_type(8)));
typedef float floatx4 __attribute__((ext_vector_type(4)));

// ---------------- fused global amax (x and W in one launch) ----------------
__global__ void amax_both_k(const float4* __restrict__ x, long nx4,
                            const float4* __restrict__ w, long nw4,
                            unsigned* slots, int gx) {
    const float4* src; long n4; int bid, nb; unsigned* slot;
    if ((int)blockIdx.x < gx) { src = x; n4 = nx4; bid = blockIdx.x; nb = gx; slot = slots; }
    else { src = w; n4 = nw4; bid = blockIdx.x - gx; nb = gridDim.x - gx; slot = slots + 1; }
    float m = 0.0f;
    long stride = (long)nb * blockDim.x;
    for (long i = (long)bid * blockDim.x + threadIdx.x; i < n4; i += stride) {
        float4 v = src[i];
        m = fmaxf(m, fmaxf(fmaxf(fabsf(v.x), fabsf(v.y)), fmaxf(fabsf(v.z), fabsf(v.w))));
    }
    #pragma unroll
    for (int off = 32; off > 0; off >>= 1)
        m = fmaxf(m, __shfl_down(m, off, 64));
    __shared__ float sm[4];
    int lane = threadIdx.x & 63, wv = threadIdx.x >> 6;
    if (lane == 0) sm[wv] = m;
    __syncthreads();
    if (threadIdx.x == 0) {
        m = fmaxf(fmaxf(sm[0], sm[1]), fmaxf(sm[2], sm[3]));
        atomicMax(slot, __float_as_uint(m));   // nonneg fp32: uint order == float order
    }
}

// ---------------- quantization helpers ----------------
// RNE float -> e4m3fn for v in [0, 448]
__device__ __forceinline__ float e4m3_rne(float v) {
    unsigned u = __float_as_uint(v);
    u += 0x7FFFFu + ((u >> 20) & 1u);            // RNE keep 3 mantissa bits
    float hi = __uint_as_float(u & 0xFFF00000u);
    float lo = rintf(v * 512.0f) * 0.001953125f; // subnormal, step 2^-9
    return (v < 0.015625f) ? lo : hi;
}

// RNE to fp4 e2m1 {0,±0.5,1,1.5,2,3,4,6}
__device__ __forceinline__ float fp4_rne(float x) {
    float a = fminf(fabsf(x), 6.0f);
    unsigned u = __float_as_uint(a);
    u += 0x1FFFFFu + ((u >> 22) & 1u);           // RNE keep 1 mantissa bit (a >= 1)
    float hi = __uint_as_float(u & 0xFFC00000u);
    float lo = rintf(a + a) * 0.5f;              // a < 1: fixed step 0.5
    float q = (a < 1.0f) ? lo : hi;
    return copysignf(q, x);
}

// pack two fp32 (exactly representable in bf16) into 2 bf16 bit patterns
__device__ __forceinline__ unsigned pack2(float d0, float d1) {
    return (__float_as_uint(d0) >> 16) | (__float_as_uint(d1) & 0xFFFF0000u);
}

// One thread per 16-elem nvfp4 block; handles both tensors in one launch.
__global__ void quant_both_k(const float* __restrict__ x, const float* __restrict__ W,
                             u16* __restrict__ Aq, u16* __restrict__ Bq,
                             const unsigned* __restrict__ slots, long nbx, long nbtot) {
    long b = (long)blockIdx.x * blockDim.x + threadIdx.x;
    if (b >= nbtot) return;
    const float* src; u16* dst; float ag;
    if (b < nbx) { src = x + b * 16; dst = Aq + b * 16; ag = __uint_as_float(slots[0]); }
    else { long c = b - nbx; src = W + c * 16; dst = Bq + c * 16; ag = __uint_as_float(slots[1]); }
    float gs = 2688.0f / ag;       // same fp32 ops as reference
    float t  = gs / 6.0f;          // reference computes gs/F4_MAX first
    const float4* p = (const float4*)src;
    float4 v0 = p[0], v1 = p[1], v2 = p[2], v3 = p[3];
    float am = 0.0f;
    am = fmaxf(am, fmaxf(fmaxf(fabsf(v0.x), fabsf(v0.y)), fmaxf(fabsf(v0.z), fabsf(v0.w))));
    am = fmaxf(am, fmaxf(fmaxf(fabsf(v1.x), fabsf(v1.y)), fmaxf(fabsf(v1.z), fabsf(v1.w))));
    am = fmaxf(am, fmaxf(fmaxf(fabsf(v2.x), fabsf(v2.y)), fmaxf(fabsf(v2.z), fabsf(v2.w))));
    am = fmaxf(am, fmaxf(fmaxf(fabsf(v3.x), fabsf(v3.y)), fmaxf(fabsf(v3.z), fabsf(v3.w))));
    float sf = e4m3_rne(am * t);
    float r = gs / (sf > 0.0f ? sf : 1.0f);      // reference: gs/safe, then v*r
    uint4 o0, o1;
    o0.x = pack2(fp4_rne(v0.x * r) * sf, fp4_rne(v0.y * r) * sf);
    o0.y = pack2(fp4_rne(v0.z * r) * sf, fp4_rne(v0.w * r) * sf);
    o0.z = pack2(fp4_rne(v1.x * r) * sf, fp4_rne(v1.y * r) * sf);
    o0.w = pack2(fp4_rne(v1.z * r) * sf, fp4_rne(v1.w * r) * sf);
    o1.x = pack2(fp4_rne(v2.x * r) * sf, fp4_rne(v2.y * r) * sf);
    o1.y = pack2(fp4_rne(v2.z * r) * sf, fp4_rne(v2.w * r) * sf);
    o1.z = pack2(fp4_rne(v3.x * r) * sf, fp4_rne(v3.y * r) * sf);
    o1.w = pack2(fp4_rne(v3.z * r) * sf, fp4_rne(v3.w * r) * sf);
    uint4* q = (uint4*)dst;
    q[0] = o0; q[1] = o1;
}

// ---------------- GEMM: 256x256 tile, BK=64, 8-phase counted-vmcnt schedule ----------------
// R4 change (single variable): fragment loads are now INLINE-ASM ds_read_b128.
// Evidence (R4 profile): bank-conflict 0 but MfmaUtil stuck at 37.6% / 914 TF = m97-class
// drain signature -> compiler auto-inserts s_waitcnt vmcnt(0) before C++ ds_reads that may
// alias pending global_load_lds (LDS-DMA tracking), defeating the counted-vmcnt pipeline.
// Inline-asm ds_read is opaque to the waitcnt pass; we manage lgkmcnt manually:
// each phase = [asm ds_reads + stage issue] BAR [lgkmcnt(0); sched_barrier; MFMA] BAR.
// Stage schedule per tile s (half-tile = 128 rows x 64 cols per phase):
//   ph1: A(s+1)h0 -> bufA[CUR^1]   ph2: A(s+1)h1
//   ph3: B(s+2)h0 -> bufB[CUR]     ph4: B(s+2)h1, then vmcnt(4) (leaves B(s+2) in flight)
// Reads of a buffer complete at that phase's lgkmcnt(0), which precedes the trailing
// barrier, which precedes any overwriting DMA issue -> WAR safe.
#define KTILE 64

#define SFENCE() __builtin_amdgcn_sched_barrier(0)
#define BAR() do { asm volatile("" ::: "memory"); SFENCE(); \
    __builtin_amdgcn_s_barrier(); SFENCE(); asm volatile("" ::: "memory"); } while (0)
#define LGKM0() do { asm volatile("s_waitcnt lgkmcnt(0)" ::: "memory"); SFENCE(); } while (0)

// inline-asm ds_read_b128: opaque to SIInsertWaitcnts (no auto vmcnt(0) before it)
#define DSR128(D, P) asm volatile("ds_read_b128 %0, %1" : "=v"(D) \
    : "v"((unsigned)(unsigned long long)(const __attribute__((address_space(3))) void*)(const void*)(P)))

#define STAGE_SLOT(GS, LS) do { \
    __builtin_amdgcn_global_load_lds((const __attribute__((address_space(1))) void*)(GS), \
        (__attribute__((address_space(3))) void*)(LS), 16, 0, 0); \
    __builtin_amdgcn_global_load_lds((const __attribute__((address_space(1))) void*)((GS) + row64K), \
        (__attribute__((address_space(3))) void*)((LS) + 4096), 16, 0, 0); \
} while (0)

#define LDA(CUR, MH) do { \
    _Pragma("unroll") for (int mf = 0; mf < 4; ++mf) { \
        const u16* p_ = aB + (CUR) * 16384 + ((MH) * 64 + mf * 16) * 64; \
        DSR128(af[mf][0], p_ + ca0 * 8); \
        DSR128(af[mf][1], p_ + ca1 * 8); \
    } } while (0)

#define LDB(CUR, NH) do { \
    _Pragma("unroll") for (int nf = 0; nf < 2; ++nf) { \
        const u16* p_ = bB + (CUR) * 16384 + ((NH) * 32 + nf * 16) * 64; \
        DSR128(bf[(NH)*2+nf][0], p_ + ca0 * 8); \
        DSR128(bf[(NH)*2+nf][1], p_ + ca1 * 8); \
    } } while (0)

#define QUAD(MH, NH) do { \
    _Pragma("unroll") for (int ks = 0; ks < 2; ++ks) \
    _Pragma("unroll") for (int mf = 0; mf < 4; ++mf) \
    _Pragma("unroll") for (int nf = 0; nf < 2; ++nf) \
        acc[(MH)*4+mf][(NH)*2+nf] = __builtin_amdgcn_mfma_f32_16x16x32_bf16( \
            af[mf][ks], bf[(NH)*2+nf][ks], acc[(MH)*4+mf][(NH)*2+nf], 0, 0, 0); \
} while (0)

#define TILE(CUR, S) do { \
    const u16* gA1 = Ag + (size_t)(((S)+1 < NT) ? (S)+1 : NT-1) * KTILE; \
    const u16* gB2 = Bg + (size_t)(((S)+2 < NT) ? (S)+2 : NT-1) * KTILE; \
    u16* lA1 = Al + ((CUR)^1) * 16384; \
    u16* lB2 = Bl + (CUR) * 16384; \
    /* phase 1: quadrant (0,0) */ \
    LDA(CUR, 0); LDB(CUR, 0); \
    STAGE_SLOT(gA1, lA1); \
    BAR(); \
    LGKM0(); \
    __builtin_amdgcn_s_setprio(1); QUAD(0, 0); __builtin_amdgcn_s_setprio(0); \
    BAR(); \
    /* phase 2: quadrant (0,1) */ \
    LDB(CUR, 1); \
    STAGE_SLOT(gA1 + halfGA, lA1 + 8192); \
    BAR(); \
    LGKM0(); \
    __builtin_amdgcn_s_setprio(1); QUAD(0, 1); __builtin_amdgcn_s_setprio(0); \
    BAR(); \
    /* phase 3: quadrant (1,0) */ \
    LDA(CUR, 1); \
    STAGE_SLOT(gB2, lB2); \
    BAR(); \
    LGKM0(); \
    __builtin_amdgcn_s_setprio(1); QUAD(1, 0); __builtin_amdgcn_s_setprio(0); \
    BAR(); \
    /* phase 4: quadrant (1,1) + per-tile counted-vmcnt checkpoint */ \
    STAGE_SLOT(gB2 + halfGA, lB2 + 8192); \
    BAR(); \
    __builtin_amdgcn_s_setprio(1); QUAD(1, 1); __builtin_amdgcn_s_setprio(0); \
    SFENCE(); \
    asm volatile("s_waitcnt vmcnt(4)" ::: "memory"); \
    BAR(); \
} while (0)

__global__ __launch_bounds__(512, 2) void gemm_k(
    const u16* __restrict__ A, const u16* __restrict__ B,
    const float* __restrict__ bias, const unsigned* __restrict__ scal,
    float* __restrict__ out, int M, int N, int K)
{
    __shared__ u16 As[2 * 256 * 64];   // 64 KB
    __shared__ u16 Bs[2 * 256 * 64];   // 64 KB

    const int tid = threadIdx.x;       // 0..511
    const int l   = tid & 63;
    const int wv  = tid >> 6;          // 0..7
    const int wm  = wv >> 2;           // 0..1  (M half)
    const int wn  = wv & 3;            // 0..3  (N quarter)

    // XCD-aware bijective block swizzle (m204)
    const int nTM = M / 256, nTN = N / 256;
    const int nwg = nTM * nTN;
    const int orig = blockIdx.x;
    const int xcd = orig & 7, lid = orig >> 3;
    const int q8 = nwg >> 3, r8 = nwg & 7;
    const int swz = (xcd < r8 ? xcd * (q8 + 1) : r8 * (q8 + 1) + (xcd - r8) * q8) + lid;
    const long tileM = (long)(swz % nTM) * 256;
    const long tileN = (long)(swz / nTM) * 256;

    // ---- staging addresses (per-lane global src, wave-uniform LDS dst) ----
    const int srow  = tid >> 3;              // 0..63 within half
    const int sslot = tid & 7;               // 16B chunk slot
    const int schunk = sslot ^ (srow & 7);   // inverse-swizzled source chunk
    const size_t row64K = (size_t)64 * K;
    const size_t halfGA = (size_t)128 * K;
    const u16* Ag = A + (size_t)(tileM + srow) * K + schunk * 8;
    const u16* Bg = B + (size_t)(tileN + srow) * K + schunk * 8;
    u16* Al = As + wv * 512;                 // wave-linear dest (base + lane*16B)
    u16* Bl = Bs + wv * 512;

    // ---- ds_read addresses (16x16x32 frag: row = l&15, kchunk = l>>4) ----
    const int lr = l & 15;
    const int hi = l >> 4;
    const int ca0 = hi ^ (lr & 7);           // swizzled chunk, ks=0
    const int ca1 = ca0 ^ 4;                 // ks=1 toggles chunk bit2
    const u16* aB = As + (wm * 128 + lr) * 64;
    const u16* bB = Bs + (wn * 64 + lr) * 64;

    floatx4 acc[8][4] = {};
    bf16x8 af[4][2], bf[4][2];

    const int NT = K / KTILE;                // must be even (K % 128 == 0)

    // ---- prologue: B(0), A(0), B(1); leave B(1) (last 4 slots) in flight ----
    STAGE_SLOT(Bg, Bl);
    STAGE_SLOT(Bg + halfGA, Bl + 8192);
    STAGE_SLOT(Ag, Al);
    STAGE_SLOT(Ag + halfGA, Al + 8192);
    {
        const u16* gB1 = Bg + ((1 < NT) ? KTILE : 0);
        STAGE_SLOT(gB1, Bl + 16384);
        STAGE_SLOT(gB1 + halfGA, Bl + 16384 + 8192);
    }
    SFENCE();
    asm volatile("s_waitcnt vmcnt(4)" ::: "memory");
    BAR();

    for (int s = 0; s < NT; s += 2) {
        TILE(0, s);
        TILE(1, s + 1);
    }

    // ---- epilogue ----
    float ax = __uint_as_float(scal[0]);
    float aw = __uint_as_float(scal[1]);
    float gsx = 2688.0f / ax, gsw = 2688.0f / aw;
    float alpha = 1.0f / (gsx * gsw);

    // C/D (m89): col = lane&15, row = (lane>>4)*4 + reg
    #pragma unroll
    for (int nq = 0; nq < 4; ++nq) {
        const long col = tileN + wn * 64 + nq * 16 + lr;
        const float bv = bias[col];
        #pragma unroll
        for (int mq = 0; mq < 8; ++mq) {
            const long r0 = tileM + wm * 128 + mq * 16 + hi * 4;
            #pragma unroll
            for (int reg = 0; reg < 4; ++reg)
                out[(size_t)(r0 + reg) * N + col] = acc[mq][nq][reg] * alpha + bv;
        }
    }
}

// ---------------- launch ----------------
extern "C" void kernel_launch(void* const* d_in, const int* in_sizes, int n_in,
                              void* d_out, int out_size, void* d_ws, size_t ws_size,
                              hipStream_t stream) {
    const float* x    = (const float*)d_in[0];
    const float* W    = (const float*)d_in[1];
    const float* bias = (const float*)d_in[2];
    float* out = (float*)d_out;

    const int N = in_sizes[2];
    const int K = in_sizes[1] / N;
    const int M = in_sizes[0] / K;

    unsigned* scal = (unsigned*)d_ws;
    u16* Aq = (u16*)((char*)d_ws + 256);
    u16* Bq = Aq + (size_t)M * K;

    hipMemsetAsync(scal, 0, 8, stream);

    const int GX = 2048, GW = 1024;
    hipLaunchKernelGGL(amax_both_k, dim3(GX + GW), dim3(256), 0, stream,
                       (const float4*)x, (long)M * K / 4,
                       (const float4*)W, (long)N * K / 4, scal, GX);

    long nbx = (long)M * K / 16;
    long nbw = (long)N * K / 16;
    hipLaunchKernelGGL(quant_both_k, dim3((unsigned)((nbx + nbw + 255) / 256)), dim3(256), 0, stream,
                       x, W, Aq, Bq, scal, nbx, nbx + nbw);

    hipLaunchKernelGGL(gemm_k, dim3((M / 256) * (N / 256)), dim3(512), 0, stream,
                       Aq, Bq, bias, scal, out, M, N, K);
}